// Round 3
// baseline (1656.175 us; speedup 1.0000x reference)
//
#include <hip/hip_runtime.h>
#include <stdint.h>

typedef __attribute__((ext_vector_type(8))) short short8;
typedef __attribute__((ext_vector_type(4))) float f32x4;
typedef unsigned short u16;
typedef unsigned int u32;

#define NPER 6

// ws (bf16) element offsets
#define SW_OFF  0
#define TRW_OFF 131072
#define TW1_OFF 196608
#define CRW_OFF 262144
#define CW1_OFF 327680
#define TW2_OFF 393216
#define CW2_OFF 397312
#define CONV_N  401408      // weight elems; h16 follows at ws + CONV_N

__device__ inline u16 f2b(float f){                 // f32 -> bf16 (RNE)
  u32 u = __builtin_bit_cast(u32, f);
  u = u + 0x7FFFu + ((u >> 16) & 1u);
  return (u16)(u >> 16);
}
__device__ inline float b2f(u16 v){ return __builtin_bit_cast(float, ((u32)v) << 16); }
__device__ inline float elu1(float x){ return x > 0.f ? x : (__expf(x) - 1.f); }

__global__ __launch_bounds__(256) void convert_weights(
    const float* __restrict__ sw, const float* __restrict__ trw, const float* __restrict__ tw1,
    const float* __restrict__ crw, const float* __restrict__ cw1,
    const float* __restrict__ tw2, const float* __restrict__ cw2, u16* __restrict__ ws){
  int i = blockIdx.x * 256 + threadIdx.x;
  if (i >= CONV_N) return;
  float v;
  if (i < TRW_OFF) {
    v = sw[i];
  } else if (i < TW2_OFF) {
    int j = i - TRW_OFF; int m = j >> 16; int jj = j & 65535;
    const float* src = (m == 0) ? trw : (m == 1) ? tw1 : (m == 2) ? crw : cw1;
    v = src[jj];
  } else {
    int j = i - TW2_OFF;
    const float* src = (j < 4096) ? tw2 : cw2;
    int jj = j & 4095; int row = jj >> 8, col = jj & 255;
    v = (row < NPER) ? src[row * 256 + col] : 0.f;   // zero-pad rows 6..15
  }
  ws[i] = f2b(v);
}

__global__ __launch_bounds__(256) void convert_h(
    const float* __restrict__ h, u16* __restrict__ h16, int n8){
  int i = blockIdx.x * 256 + threadIdx.x;
  if (i >= n8) return;
  const float4* src = (const float4*)(h + (size_t)i * 8);
  float4 q0 = src[0], q1 = src[1];
  short8 v;
  v[0]=(short)f2b(q0.x); v[1]=(short)f2b(q0.y); v[2]=(short)f2b(q0.z); v[3]=(short)f2b(q0.w);
  v[4]=(short)f2b(q1.x); v[5]=(short)f2b(q1.y); v[6]=(short)f2b(q1.z); v[7]=(short)f2b(q1.w);
  *(short8*)(h16 + (size_t)i * 8) = v;
}

// 32x64 wave-tile GEMM, K=256, A in swizzled LDS (row stride 512B), W bf16 [256][256]
__device__ inline void gemm256(const char* __restrict__ A, const u16* __restrict__ Wp,
                               f32x4 (&acc)[2][4], int w, int lr, int lg){
  #pragma unroll
  for (int ks = 0; ks < 8; ++ks){
    short8 a[2];
    #pragma unroll
    for (int mf = 0; mf < 2; ++mf){
      const int row = mf * 16 + lr;
      a[mf] = *(const short8*)(A + row * 512 + ((ks * 64 + lg * 16) ^ ((row & 7) << 4)));
    }
    const int kW = ks * 32 + lg * 8;
    #pragma unroll
    for (int nf = 0; nf < 4; ++nf){
      short8 b = *(const short8*)(Wp + (size_t)(w * 64 + nf * 16 + lr) * 256 + kW);
      #pragma unroll
      for (int mf = 0; mf < 2; ++mf)
        acc[mf][nf] = __builtin_amdgcn_mfma_f32_16x16x32_bf16(a[mf], b, acc[mf][nf], 0, 0, 0);
    }
  }
}

#define ZERO_ACC(acc) { _Pragma("unroll") for (int mf_ = 0; mf_ < 2; ++mf_) \
  _Pragma("unroll") for (int nf_ = 0; nf_ < 4; ++nf_) acc[mf_][nf_] = (f32x4){0.f,0.f,0.f,0.f}; }

// stage chunk c (compile-time): [32 rows][64 k] bf16, XOR-swizzled, into Zb buf c%3
#define LOADC(c, dst) { \
  const int node_ = (((c) >> 1) == 0) ? idx4.x : (((c) >> 1) == 1) ? idx4.y : (((c) >> 1) == 2) ? idx4.z : idx4.w; \
  const size_t off_ = (size_t)node_ * 128 + ((c) & 1) * 64 + sg * 8; \
  if (H16) { dst = *(const short8*)(h16 + off_); } \
  else { float4 q0_ = *(const float4*)(h + off_); float4 q1_ = *(const float4*)(h + off_ + 4); \
    dst[0]=(short)f2b(q0_.x); dst[1]=(short)f2b(q0_.y); dst[2]=(short)f2b(q0_.z); dst[3]=(short)f2b(q0_.w); \
    dst[4]=(short)f2b(q1_.x); dst[5]=(short)f2b(q1_.y); dst[6]=(short)f2b(q1_.z); dst[7]=(short)f2b(q1_.w); } }
#define STOREC(c, src) \
  *(short8*)(Zb + ((c) % 3) * 4096 + srow * 128 + ((sg * 16) ^ ((srow & 7) << 4))) = src;

template<bool H16>
__global__ __launch_bounds__(256, 4) void torsion_kernel(
    const float* __restrict__ h, const u16* __restrict__ h16,
    const int* __restrict__ idxs, const float* __restrict__ sb,
    const float* __restrict__ t_rb, const float* __restrict__ t_b1, const float* __restrict__ t_b2,
    const float* __restrict__ c_rb, const float* __restrict__ c_b1, const float* __restrict__ c_b2,
    const u16* __restrict__ ws, float* __restrict__ out, int NT)
{
  // 16K + 16K + 2K + 2K = 36 KB -> 4 blocks/CU
  __shared__ __attribute__((aligned(16))) char Xb[16384];   // [32][256] bf16 swizzled
  __shared__ __attribute__((aligned(16))) char Zb[16384];   // gather tri-buf (3x4K) then Y/V
  __shared__ float SC[512];                                 // [32][16] f32 score
  __shared__ float CO[512];                                 // [32][16] f32 coeffs

  const int tid = threadIdx.x, blk = blockIdx.x;
  const int lane = tid & 63, lr = lane & 15, lg = lane >> 4;
  const int w = tid >> 6;                     // wave 0..3 -> cols w*64..w*64+63

  // staging geometry: thread stages row srow, 16B granule sg
  const int srow = tid >> 3;                  // 0..31
  const int sg = tid & 7;
  const int grow = blk * 32 + srow;
  int4 idx4 = (grow < NT) ? ((const int4*)idxs)[grow] : (int4){0,0,0,0};

  f32x4 acc[2][4];
  ZERO_ACC(acc);

  // ---------------- stage A: x = elu(concat(h[idx]) @ sw.T + sb), K=512 ----------------
  short8 rg0, rg1;
  LOADC(0, rg0); STOREC(0, rg0);
  LOADC(1, rg1);
  LOADC(2, rg0);
  __syncthreads();

  #pragma unroll
  for (int c = 0; c < 8; ++c){
    const char* cur = Zb + (c % 3) * 4096;
    #pragma unroll
    for (int kk = 0; kk < 2; ++kk){
      short8 a[2];
      #pragma unroll
      for (int mf = 0; mf < 2; ++mf){
        const int row = mf * 16 + lr;
        a[mf] = *(const short8*)(cur + row * 128 + ((kk * 64 + lg * 16) ^ ((row & 7) << 4)));
      }
      const int kW = c * 64 + kk * 32 + lg * 8;
      #pragma unroll
      for (int nf = 0; nf < 4; ++nf){
        short8 b = *(const short8*)(ws + SW_OFF + (size_t)(w * 64 + nf * 16 + lr) * 512 + kW);
        #pragma unroll
        for (int mf = 0; mf < 2; ++mf)
          acc[mf][nf] = __builtin_amdgcn_mfma_f32_16x16x32_bf16(a[mf], b, acc[mf][nf], 0, 0, 0);
      }
    }
    if (c == 0){ STOREC(1, rg1); LOADC(3, rg1); }
    else if (c == 1){ STOREC(2, rg0); LOADC(4, rg0); }
    else if (c == 2){ STOREC(3, rg1); LOADC(5, rg1); }
    else if (c == 3){ STOREC(4, rg0); LOADC(6, rg0); }
    else if (c == 4){ STOREC(5, rg1); LOADC(7, rg1); }
    else if (c == 5){ STOREC(6, rg0); }
    else if (c == 6){ STOREC(7, rg1); }
    __syncthreads();
  }

  // finalize X -> swizzled bf16 Xb (residual re-read later; no register carry)
  #pragma unroll
  for (int nf = 0; nf < 4; ++nf){
    const int col = w * 64 + nf * 16 + lr;
    const float bias = sb[col];
    #pragma unroll
    for (int mf = 0; mf < 2; ++mf)
      #pragma unroll
      for (int r = 0; r < 4; ++r){
        const int row = mf * 16 + lg * 4 + r;
        *(u16*)(Xb + row * 512 + ((col * 2) ^ ((row & 7) << 4))) = f2b(elu1(acc[mf][nf][r] + bias));
      }
  }
  __syncthreads();

  // ---------------- heads (sequential; Zb shared for Y then V) ----------------
  #pragma unroll 1
  for (int hd = 0; hd < 2; ++hd){
    const u16* RW = ws + (hd ? TRW_OFF : CRW_OFF);
    const u16* W1 = ws + (hd ? TW1_OFF : CW1_OFF);
    const u16* W2 = ws + (hd ? TW2_OFF : CW2_OFF);
    const float* RB = hd ? t_rb : c_rb;
    const float* B1 = hd ? t_b1 : c_b1;
    const float* B2 = hd ? t_b2 : c_b2;

    // y = x + elu(x @ rw.T + rb)
    ZERO_ACC(acc);
    gemm256((const char*)Xb, RW, acc, w, lr, lg);
    if (hd == 1) __syncthreads();     // protect head-0's W2 reads of Zb(V) before overwrite
    #pragma unroll
    for (int nf = 0; nf < 4; ++nf){
      const int col = w * 64 + nf * 16 + lr;
      const float bias = RB[col];
      #pragma unroll
      for (int mf = 0; mf < 2; ++mf)
        #pragma unroll
        for (int r = 0; r < 4; ++r){
          const int row = mf * 16 + lg * 4 + r;
          const float xv = b2f(*(const u16*)(Xb + row * 512 + ((col * 2) ^ ((row & 7) << 4))));
          const float yv = xv + elu1(acc[mf][nf][r] + bias);
          *(u16*)(Zb + row * 512 + ((col * 2) ^ ((row & 7) << 4))) = f2b(yv);
        }
    }
    __syncthreads();

    // v = elu(y @ w1.T + b1): compute to regs, then overwrite Zb
    ZERO_ACC(acc);
    gemm256((const char*)Zb, W1, acc, w, lr, lg);
    __syncthreads();                  // all Zb(Y) reads done
    #pragma unroll
    for (int nf = 0; nf < 4; ++nf){
      const int col = w * 64 + nf * 16 + lr;
      const float bias = B1[col];
      #pragma unroll
      for (int mf = 0; mf < 2; ++mf)
        #pragma unroll
        for (int r = 0; r < 4; ++r){
          const int row = mf * 16 + lg * 4 + r;
          *(u16*)(Zb + row * 512 + ((col * 2) ^ ((row & 7) << 4))) = f2b(elu1(acc[mf][nf][r] + bias));
        }
    }
    __syncthreads();                  // V ready

    // out16 = v @ w2p.T (zero-padded [16][256]); one wave per head, full K, no reduction
    if (w == hd){
      f32x4 a2[2];
      a2[0] = (f32x4){0.f,0.f,0.f,0.f}; a2[1] = (f32x4){0.f,0.f,0.f,0.f};
      #pragma unroll
      for (int ks = 0; ks < 8; ++ks){
        short8 b = *(const short8*)(W2 + (size_t)lr * 256 + ks * 32 + lg * 8);
        #pragma unroll
        for (int mf = 0; mf < 2; ++mf){
          const int row = mf * 16 + lr;
          short8 a = *(const short8*)(Zb + row * 512 + ((ks * 64 + lg * 16) ^ ((row & 7) << 4)));
          a2[mf] = __builtin_amdgcn_mfma_f32_16x16x32_bf16(a, b, a2[mf], 0, 0, 0);
        }
      }
      float* R = hd ? CO : SC;
      const float bias2 = (lr < NPER) ? B2[lr] : 0.f;
      #pragma unroll
      for (int mf = 0; mf < 2; ++mf)
        #pragma unroll
        for (int r = 0; r < 4; ++r)
          R[(mf * 16 + lg * 4 + r) * 16 + lr] = a2[mf][r] + bias2;
    }
  }
  __syncthreads();

  // ---------------- epilogue ----------------
  if (tid < 192){
    const int row = tid / 6, col = tid - row * 6;
    const int g = blk * 32 + row;
    if (g < NT){
      const float s = SC[row * 16 + col];
      const float c0 = CO[row * 16 + col];
      out[(size_t)g * 6 + col] = s;
      out[(size_t)NT * 6 + (size_t)g * 6 + col] = c0 * 1e-3f * (1.f / (1.f + __expf(-s)));
    }
  }
}

extern "C" void kernel_launch(void* const* d_in, const int* in_sizes, int n_in,
                              void* d_out, int out_size, void* d_ws, size_t ws_size,
                              hipStream_t stream){
  const float* h    = (const float*)d_in[0];
  const int*   idxs = (const int*)d_in[1];
  const float* sw   = (const float*)d_in[2];
  const float* sb   = (const float*)d_in[3];
  const float* trw  = (const float*)d_in[4];
  const float* trb  = (const float*)d_in[5];
  const float* tw1  = (const float*)d_in[6];
  const float* tb1  = (const float*)d_in[7];
  const float* tw2  = (const float*)d_in[8];
  const float* tb2  = (const float*)d_in[9];
  const float* crw  = (const float*)d_in[10];
  const float* crb  = (const float*)d_in[11];
  const float* cw1  = (const float*)d_in[12];
  const float* cb1  = (const float*)d_in[13];
  const float* cw2  = (const float*)d_in[14];
  const float* cb2  = (const float*)d_in[15];
  u16* ws    = (u16*)d_ws;
  float* out = (float*)d_out;
  const int NT = in_sizes[1] / 4;
  const int nh = in_sizes[0];                       // N_NODES * 128
  const bool useH16 = ws_size >= (size_t)(CONV_N + nh) * 2;

  hipLaunchKernelGGL(convert_weights, dim3((CONV_N + 255) / 256), dim3(256), 0, stream,
                     sw, trw, tw1, crw, cw1, tw2, cw2, ws);
  u16* h16 = ws + CONV_N;
  const int nblk = (NT + 31) / 32;
  if (useH16){
    const int n8 = nh / 8;
    hipLaunchKernelGGL(convert_h, dim3((n8 + 255) / 256), dim3(256), 0, stream, h, h16, n8);
    torsion_kernel<true><<<dim3(nblk), dim3(256), 0, stream>>>(
        h, h16, idxs, sb, trb, tb1, tb2, crb, cb1, cb2, ws, out, NT);
  } else {
    torsion_kernel<false><<<dim3(nblk), dim3(256), 0, stream>>>(
        h, h16, idxs, sb, trb, tb1, tb2, crb, cb1, cb2, ws, out, NT);
  }
}

// Round 4
// 1084.816 us; speedup vs baseline: 1.5267x; 1.5267x over previous
//
#include <hip/hip_runtime.h>
#include <stdint.h>

typedef __attribute__((ext_vector_type(8))) short short8;
typedef __attribute__((ext_vector_type(4))) float f32x4;
typedef unsigned short u16;
typedef unsigned int u32;

#define NPER 6

// ws (bf16) element offsets
#define SW_OFF  0
#define TRW_OFF 131072
#define TW1_OFF 196608
#define CRW_OFF 262144
#define CW1_OFF 327680
#define TW2_OFF 393216
#define CW2_OFF 397312
#define CONV_N  401408      // weight elems; h16 follows at ws + CONV_N

__device__ inline u16 f2b(float f){                 // f32 -> bf16 (RNE)
  u32 u = __builtin_bit_cast(u32, f);
  u = u + 0x7FFFu + ((u >> 16) & 1u);
  return (u16)(u >> 16);
}
__device__ inline float b2f(u16 v){ return __builtin_bit_cast(float, ((u32)v) << 16); }
__device__ inline float elu1(float x){ return x > 0.f ? x : (__expf(x) - 1.f); }

__global__ __launch_bounds__(256) void convert_weights(
    const float* __restrict__ sw, const float* __restrict__ trw, const float* __restrict__ tw1,
    const float* __restrict__ crw, const float* __restrict__ cw1,
    const float* __restrict__ tw2, const float* __restrict__ cw2, u16* __restrict__ ws){
  int i = blockIdx.x * 256 + threadIdx.x;
  if (i >= CONV_N) return;
  float v;
  if (i < TRW_OFF) {
    v = sw[i];
  } else if (i < TW2_OFF) {
    int j = i - TRW_OFF; int m = j >> 16; int jj = j & 65535;
    const float* src = (m == 0) ? trw : (m == 1) ? tw1 : (m == 2) ? crw : cw1;
    v = src[jj];
  } else {
    int j = i - TW2_OFF;
    const float* src = (j < 4096) ? tw2 : cw2;
    int jj = j & 4095; int row = jj >> 8, col = jj & 255;
    v = (row < NPER) ? src[row * 256 + col] : 0.f;   // zero-pad rows 6..15
  }
  ws[i] = f2b(v);
}

__global__ __launch_bounds__(256) void convert_h(
    const float* __restrict__ h, u16* __restrict__ h16, int n8){
  int i = blockIdx.x * 256 + threadIdx.x;
  if (i >= n8) return;
  const float4* src = (const float4*)(h + (size_t)i * 8);
  float4 q0 = src[0], q1 = src[1];
  short8 v;
  v[0]=(short)f2b(q0.x); v[1]=(short)f2b(q0.y); v[2]=(short)f2b(q0.z); v[3]=(short)f2b(q0.w);
  v[4]=(short)f2b(q1.x); v[5]=(short)f2b(q1.y); v[6]=(short)f2b(q1.z); v[7]=(short)f2b(q1.w);
  *(short8*)(h16 + (size_t)i * 8) = v;
}

// 64x32 wave-tile GEMM, K=256, A in swizzled LDS (row stride 512B), W bf16 [256][256]
__device__ inline void gemm256(const char* __restrict__ A, const u16* __restrict__ Wp,
                               f32x4 (&acc)[4][2], int w, int lr, int lg){
  #pragma unroll
  for (int ks = 0; ks < 8; ++ks){
    short8 a[4];
    #pragma unroll
    for (int mf = 0; mf < 4; ++mf){
      const int row = mf * 16 + lr;
      a[mf] = *(const short8*)(A + row * 512 + ((ks * 64 + lg * 16) ^ ((row & 7) << 4)));
    }
    const int kW = ks * 32 + lg * 8;
    #pragma unroll
    for (int nf = 0; nf < 2; ++nf){
      short8 b = *(const short8*)(Wp + (size_t)(w * 32 + nf * 16 + lr) * 256 + kW);
      #pragma unroll
      for (int mf = 0; mf < 4; ++mf)
        acc[mf][nf] = __builtin_amdgcn_mfma_f32_16x16x32_bf16(a[mf], b, acc[mf][nf], 0, 0, 0);
    }
  }
}

#define ZERO_ACC(acc) { _Pragma("unroll") for (int mf_ = 0; mf_ < 4; ++mf_) \
  _Pragma("unroll") for (int nf_ = 0; nf_ < 2; ++nf_) acc[mf_][nf_] = (f32x4){0.f,0.f,0.f,0.f}; }

// stage chunk c: [64 rows][64 k] bf16 into G half (c&1), XOR-swizzled
#define LOADC(c, dst) { \
  const int node_ = (((c) >> 1) == 0) ? idx4.x : (((c) >> 1) == 1) ? idx4.y : (((c) >> 1) == 2) ? idx4.z : idx4.w; \
  const size_t off_ = (size_t)node_ * 128 + ((c) & 1) * 64 + sg * 8; \
  if (H16) { dst = *(const short8*)(h16 + off_); } \
  else { float4 q0_ = *(const float4*)(h + off_); float4 q1_ = *(const float4*)(h + off_ + 4); \
    dst[0]=(short)f2b(q0_.x); dst[1]=(short)f2b(q0_.y); dst[2]=(short)f2b(q0_.z); dst[3]=(short)f2b(q0_.w); \
    dst[4]=(short)f2b(q1_.x); dst[5]=(short)f2b(q1_.y); dst[6]=(short)f2b(q1_.z); dst[7]=(short)f2b(q1_.w); } }
#define STOREC(c, src) \
  *(short8*)(G + ((c) & 1) * 8192 + srow * 128 + ((sg * 16) ^ ((srow & 7) << 4))) = src;

template<bool H16>
__global__ __launch_bounds__(512) void torsion_kernel(
    const float* __restrict__ h, const u16* __restrict__ h16,
    const int* __restrict__ idxs, const float* __restrict__ sb,
    const float* __restrict__ t_rb, const float* __restrict__ t_b1, const float* __restrict__ t_b2,
    const float* __restrict__ c_rb, const float* __restrict__ c_b1, const float* __restrict__ c_b2,
    const u16* __restrict__ ws, float* __restrict__ out, int NT)
{
  // 16K + 32K + 32K = 80 KB -> 2 blocks/CU
  __shared__ __attribute__((aligned(16))) char G[16384];    // gather dbuf 2x[64][64]; later SC/CO
  __shared__ __attribute__((aligned(16))) char Xb[32768];   // [64][256] bf16 swizzled
  __shared__ __attribute__((aligned(16))) char Zb[32768];   // [64][256] bf16 swizzled (Y then V)

  const int tid = threadIdx.x, blk = blockIdx.x;
  const int lane = tid & 63, lr = lane & 15, lg = lane >> 4;
  const int w = tid >> 6;                     // wave 0..7 -> cols w*32..w*32+31

  // staging geometry: thread stages row srow (0..63), 16B granule sg
  const int srow = tid >> 3;
  const int sg = tid & 7;
  const int grow = blk * 64 + srow;
  int4 idx4 = (grow < NT) ? ((const int4*)idxs)[grow] : (int4){0,0,0,0};

  f32x4 acc[4][2];
  ZERO_ACC(acc);

  // ---------------- stage A: x = elu(concat(h[idx]) @ sw.T + sb), K=512 ----------------
  short8 rg;
  LOADC(0, rg); STOREC(0, rg);
  __syncthreads();

  #pragma unroll
  for (int c = 0; c < 8; ++c){
    const char* cur = G + (c & 1) * 8192;
    if (c < 7) LOADC(c + 1, rg);            // issue next chunk's loads before compute
    #pragma unroll
    for (int kk = 0; kk < 2; ++kk){
      short8 a[4];
      #pragma unroll
      for (int mf = 0; mf < 4; ++mf){
        const int row = mf * 16 + lr;
        a[mf] = *(const short8*)(cur + row * 128 + ((kk * 64 + lg * 16) ^ ((row & 7) << 4)));
      }
      const int kW = c * 64 + kk * 32 + lg * 8;
      #pragma unroll
      for (int nf = 0; nf < 2; ++nf){
        short8 b = *(const short8*)(ws + SW_OFF + (size_t)(w * 32 + nf * 16 + lr) * 512 + kW);
        #pragma unroll
        for (int mf = 0; mf < 4; ++mf)
          acc[mf][nf] = __builtin_amdgcn_mfma_f32_16x16x32_bf16(a[mf], b, acc[mf][nf], 0, 0, 0);
      }
    }
    if (c < 7) STOREC(c + 1, rg);           // write after compute (latency hidden)
    __syncthreads();
  }

  // finalize X -> swizzled bf16 Xb (residual re-read later)
  #pragma unroll
  for (int nf = 0; nf < 2; ++nf){
    const int col = w * 32 + nf * 16 + lr;
    const float bias = sb[col];
    #pragma unroll
    for (int mf = 0; mf < 4; ++mf)
      #pragma unroll
      for (int r = 0; r < 4; ++r){
        const int row = mf * 16 + lg * 4 + r;
        *(u16*)(Xb + row * 512 + ((col * 2) ^ ((row & 7) << 4))) = f2b(elu1(acc[mf][nf][r] + bias));
      }
  }
  __syncthreads();

  float* SC = (float*)G;            // [64][16] f32 — gather region dead now
  float* CO = (float*)(G + 4096);

  // ---------------- heads (sequential; Zb shared for Y then V) ----------------
  #pragma unroll 1
  for (int hd = 0; hd < 2; ++hd){
    const u16* RW = ws + (hd ? TRW_OFF : CRW_OFF);
    const u16* W1 = ws + (hd ? TW1_OFF : CW1_OFF);
    const u16* W2 = ws + (hd ? TW2_OFF : CW2_OFF);
    const float* RB = hd ? t_rb : c_rb;
    const float* B1 = hd ? t_b1 : c_b1;
    const float* B2 = hd ? t_b2 : c_b2;

    // y = x + elu(x @ rw.T + rb)
    ZERO_ACC(acc);
    gemm256((const char*)Xb, RW, acc, w, lr, lg);
    if (hd == 1) __syncthreads();     // head-0's W2 reads of Zb(V) must finish first
    #pragma unroll
    for (int nf = 0; nf < 2; ++nf){
      const int col = w * 32 + nf * 16 + lr;
      const float bias = RB[col];
      #pragma unroll
      for (int mf = 0; mf < 4; ++mf)
        #pragma unroll
        for (int r = 0; r < 4; ++r){
          const int row = mf * 16 + lg * 4 + r;
          const float xv = b2f(*(const u16*)(Xb + row * 512 + ((col * 2) ^ ((row & 7) << 4))));
          *(u16*)(Zb + row * 512 + ((col * 2) ^ ((row & 7) << 4))) = f2b(xv + elu1(acc[mf][nf][r] + bias));
        }
    }
    __syncthreads();

    // v = elu(y @ w1.T + b1): compute to regs, then overwrite Zb
    ZERO_ACC(acc);
    gemm256((const char*)Zb, W1, acc, w, lr, lg);
    __syncthreads();                  // all Zb(Y) reads done
    #pragma unroll
    for (int nf = 0; nf < 2; ++nf){
      const int col = w * 32 + nf * 16 + lr;
      const float bias = B1[col];
      #pragma unroll
      for (int mf = 0; mf < 4; ++mf)
        #pragma unroll
        for (int r = 0; r < 4; ++r){
          const int row = mf * 16 + lg * 4 + r;
          *(u16*)(Zb + row * 512 + ((col * 2) ^ ((row & 7) << 4))) = f2b(elu1(acc[mf][nf][r] + bias));
        }
    }
    __syncthreads();                  // V ready

    // out16 = v @ w2p.T (zero-padded [16][256]); waves hd*4..hd*4+3, 16 rows each
    if ((w >> 2) == hd){
      const int q = w & 3;            // row group q*16..q*16+15
      f32x4 a2 = (f32x4){0.f,0.f,0.f,0.f};
      #pragma unroll
      for (int ks = 0; ks < 8; ++ks){
        const int row = q * 16 + lr;
        short8 a = *(const short8*)(Zb + row * 512 + ((ks * 64 + lg * 16) ^ ((row & 7) << 4)));
        short8 b = *(const short8*)(W2 + (size_t)lr * 256 + ks * 32 + lg * 8);
        a2 = __builtin_amdgcn_mfma_f32_16x16x32_bf16(a, b, a2, 0, 0, 0);
      }
      float* R = hd ? CO : SC;
      const float bias2 = (lr < NPER) ? B2[lr] : 0.f;
      #pragma unroll
      for (int r = 0; r < 4; ++r)
        R[(q * 16 + lg * 4 + r) * 16 + lr] = a2[r] + bias2;
    }
  }
  __syncthreads();

  // ---------------- epilogue ----------------
  if (tid < 384){
    const int row = tid / 6, col = tid - row * 6;
    const int g = blk * 64 + row;
    if (g < NT){
      const float s = SC[row * 16 + col];
      const float c0 = CO[row * 16 + col];
      out[(size_t)g * 6 + col] = s;
      out[(size_t)NT * 6 + (size_t)g * 6 + col] = c0 * 1e-3f * (1.f / (1.f + __expf(-s)));
    }
  }
}

extern "C" void kernel_launch(void* const* d_in, const int* in_sizes, int n_in,
                              void* d_out, int out_size, void* d_ws, size_t ws_size,
                              hipStream_t stream){
  const float* h    = (const float*)d_in[0];
  const int*   idxs = (const int*)d_in[1];
  const float* sw   = (const float*)d_in[2];
  const float* sb   = (const float*)d_in[3];
  const float* trw  = (const float*)d_in[4];
  const float* trb  = (const float*)d_in[5];
  const float* tw1  = (const float*)d_in[6];
  const float* tb1  = (const float*)d_in[7];
  const float* tw2  = (const float*)d_in[8];
  const float* tb2  = (const float*)d_in[9];
  const float* crw  = (const float*)d_in[10];
  const float* crb  = (const float*)d_in[11];
  const float* cw1  = (const float*)d_in[12];
  const float* cb1  = (const float*)d_in[13];
  const float* cw2  = (const float*)d_in[14];
  const float* cb2  = (const float*)d_in[15];
  u16* ws    = (u16*)d_ws;
  float* out = (float*)d_out;
  const int NT = in_sizes[1] / 4;
  const int nh = in_sizes[0];                       // N_NODES * 128
  const bool useH16 = ws_size >= (size_t)(CONV_N + nh) * 2;

  hipLaunchKernelGGL(convert_weights, dim3((CONV_N + 255) / 256), dim3(256), 0, stream,
                     sw, trw, tw1, crw, cw1, tw2, cw2, ws);
  u16* h16 = ws + CONV_N;
  const int nblk = (NT + 63) / 64;
  if (useH16){
    const int n8 = nh / 8;
    hipLaunchKernelGGL(convert_h, dim3((n8 + 255) / 256), dim3(256), 0, stream, h, h16, n8);
    torsion_kernel<true><<<dim3(nblk), dim3(512), 0, stream>>>(
        h, h16, idxs, sb, trb, tb1, tb2, crb, cb1, cb2, ws, out, NT);
  } else {
    torsion_kernel<false><<<dim3(nblk), dim3(512), 0, stream>>>(
        h, h16, idxs, sb, trb, tb1, tb2, crb, cb1, cb2, ws, out, NT);
  }
}